// Round 16
// baseline (40.615 us; speedup 1.0000x reference)
//
#include <hip/hip_runtime.h>

// Cost volume: corr[b, dyi*9+dxi, y, x] = sum_c f1[b,c,y,x] * f2[b,c,y+dyi-4,x+dxi-4]
// (OOB f2 = 0). B=4, C=256, H=W=96, patch 9x9.
//
// Round 16 = round 15 (best: 38.5us) + main software pipelining:
//  (1) ldso separated from lds_a (15.2 KB total) -> no barrier between A-frag
//      ds_reads and the MFMA loop; dy0's B loads issue alongside A ds_reads.
//  (2) half-dy double-buffer: each dy's 16 B-loads split into two 8-load
//      halves (ks 0-3 / 4-7); named P/Q buffers; 6-step static schedule
//      {MFMA(cur); issue(next)} -> one exposed L2 latency per wave (was 3-4).
//      VGPR ~120 (under the 128 occupancy step); all indices constant.
//  Pack (f2-only channel-major f16), A LDS-staging, writeout, swizzles
//  unchanged from R15.

typedef _Float16 f16x8 __attribute__((ext_vector_type(8)));
typedef float f32x4 __attribute__((ext_vector_type(4)));

#define NB 4
#define NC 256
#define NH 96
#define NW 96
#define NP 9
#define PLANE (NH * NW)                       // 9216
#define TENS (NB * NH * NW * NC)              // 9,437,184 f16 (f2 only)
#define WS_NEED ((unsigned long long)TENS * 2ull)  // 18,874,368 B
#define TPT4 (TENS / 32)                      // 294,912 pack threads
#define PACK_BLK (TPT4 / 256)                 // 1152
#define MAIN_BLK 2304                         // 4b * 96y * 6mt
#define CGSTR (NW * 8)                        // 768 f16 per cg-plane
#define ROWSTR (32 * CGSTR)                   // 24576 f16 per (b,y) row
#define AROW 272                              // A-tile row stride in f16 (544 B)
#define LPAD 37                               // fallback kernel pad

// ---------- prepass: f2 f32 [b][c][y][x] -> f16 [b][y][cg][x][8] ------------
__global__ __launch_bounds__(256) void pack_f2(const float* __restrict__ f2,
                                               _Float16* __restrict__ ws)
{
    const int e   = blockIdx.x * 256 + threadIdx.x;   // 0 .. 294,911
    const int row = e / 768;                          // b*96 + y   (384)
    const int q   = e % 768;
    const int cg  = q / 24;                           // 0..31
    const int x4  = q % 24;                           // lane-fastest (coalesced)
    const int b   = row / NH;
    const int y   = row % NH;

    const float* sp = f2 + ((size_t)(b * NC + cg * 8) * NH + y) * NW + x4 * 4;
    float vv[8][4];
#pragma unroll
    for (int j = 0; j < 8; ++j) {
        const float4 v = *(const float4*)(sp + (size_t)j * PLANE);
        vv[j][0] = v.x; vv[j][1] = v.y; vv[j][2] = v.z; vv[j][3] = v.w;
    }
    _Float16* dp = ws + ((size_t)row * 32 + cg) * CGSTR + (size_t)x4 * 32;
#pragma unroll
    for (int xi = 0; xi < 4; ++xi) {
        f16x8 o;
#pragma unroll
        for (int j = 0; j < 8; ++j) o[j] = (_Float16)vv[j][xi];
        *(f16x8*)(dp + xi * 8) = o;
    }
}

// ---------- main: MFMA banded Gram, LDS-staged A, pipelined B ---------------
__global__ __launch_bounds__(192) void costvol_mfma(const float* __restrict__ f1,
                                                    const _Float16* __restrict__ f2p,
                                                    float* __restrict__ out)
{
    __shared__ _Float16 lds_a[16 * AROW];         // 8704 B
    __shared__ float ldso[81][20];                // 6480 B (separate: no alias)

    const int bid = blockIdx.x;
    const int swz = (bid & 7) * (MAIN_BLK / 8) + (bid >> 3);
    const int mt  = swz % 6;
    const int y   = (swz / 6) % 96;
    const int b   = swz / 576;

    const int w    = threadIdx.x >> 6;            // wave 0..2 = dy-triplet
    const int lane = threadIdx.x & 63;
    const int lr   = lane & 15;
    const int lg   = lane >> 4;
    const int m0   = mt * 16;

    // --- cooperative A staging: 1024 float4 tasks over 192 threads ---------
#pragma unroll
    for (int i = 0; i < 6; ++i) {
        const int task = threadIdx.x + i * 192;   // 0..1151
        if (task < 1024) {
            const int c  = task >> 2;
            const int xq = task & 3;
            const float4 v = *(const float4*)(
                f1 + ((size_t)(b * NC + c) * NH + y) * NW + m0 + xq * 4);
            _Float16* d0 = lds_a + (size_t)(xq * 4) * AROW + c;
            d0[0 * AROW] = (_Float16)v.x;
            d0[1 * AROW] = (_Float16)v.y;
            d0[2 * AROW] = (_Float16)v.z;
            d0[3 * AROW] = (_Float16)v.w;
        }
    }
    __syncthreads();

    const int n0a = m0 - 8 + lr;                  // x' tile 0 (may be <0)
    const int n0b = m0 + 8 + lr;                  // x' tile 1 (may be >=96)
    const bool inA = (n0a >= 0);
    const bool inB = (n0b < 96);
    const f16x8 bz = {};

    // per-dy row offsets and validity (dy = w*3 + d)
    const _Float16* f2base = f2p + (size_t)(b * 96) * ROWSTR + (size_t)lg * CGSTR;
    const int y20 = y + (w * 3 + 0) - 4;
    const int y21 = y + (w * 3 + 1) - 4;
    const int y22 = y + (w * 3 + 2) - 4;
    const bool v0 = (y20 >= 0) && (y20 < 96);
    const bool v1 = (y21 >= 0) && (y21 < 96);
    const bool v2 = (y22 >= 0) && (y22 < 96);
    const ptrdiff_t ro0 = (ptrdiff_t)(v0 ? y20 : 0) * ROWSTR;
    const ptrdiff_t ro1 = (ptrdiff_t)(v1 ? y21 : 0) * ROWSTR;
    const ptrdiff_t ro2 = (ptrdiff_t)(v2 ? y22 : 0) * ROWSTR;

#define LOADH(BUF, V, RO, H)                                                   \
    {                                                                          \
        if (V) {                                                               \
            const _Float16* _ba = f2base + (RO) + (ptrdiff_t)n0a * 8;          \
            const _Float16* _bb = f2base + (RO) + (ptrdiff_t)n0b * 8;          \
            _Pragma("unroll") for (int t = 0; t < 4; ++t) {                    \
                BUF[t]     = inA ? *(const f16x8*)(_ba + ((H) * 4 + t) * 4 * CGSTR) : bz; \
                BUF[t + 4] = inB ? *(const f16x8*)(_bb + ((H) * 4 + t) * 4 * CGSTR) : bz; \
            }                                                                  \
        } else {                                                               \
            _Pragma("unroll") for (int t = 0; t < 8; ++t) BUF[t] = bz;         \
        }                                                                      \
    }

#define MFMAH(BUF, H)                                                          \
    {                                                                          \
        _Pragma("unroll") for (int t = 0; t < 4; ++t) {                        \
            acc0 = __builtin_amdgcn_mfma_f32_16x16x32_f16(a[(H) * 4 + t], BUF[t],     acc0, 0, 0, 0); \
            acc1 = __builtin_amdgcn_mfma_f32_16x16x32_f16(a[(H) * 4 + t], BUF[t + 4], acc1, 0, 0, 0); \
        }                                                                      \
    }

#define STAGE(D)                                                               \
    {                                                                          \
        const int dyv = w * 3 + (D);                                           \
        _Pragma("unroll") for (int reg = 0; reg < 4; ++reg) {                  \
            const int mrow = lg * 4 + reg;                                     \
            const int dx0  = lr - mrow - 4;                                    \
            const int dx1  = dx0 + 16;                                         \
            if (dx0 >= 0 && dx0 <= 8) ldso[dyv * 9 + dx0][mrow] = acc0[reg];   \
            if (dx1 >= 0 && dx1 <= 8) ldso[dyv * 9 + dx1][mrow] = acc1[reg];   \
        }                                                                      \
        acc0 = (f32x4){0.f, 0.f, 0.f, 0.f};                                   \
        acc1 = (f32x4){0.f, 0.f, 0.f, 0.f};                                   \
    }

    f16x8 P[8], Q[8];
    f32x4 acc0 = {0.f, 0.f, 0.f, 0.f};
    f32x4 acc1 = {0.f, 0.f, 0.f, 0.f};

    // issue first two half-batches BEFORE the A ds_reads (overlap latencies)
    LOADH(P, v0, ro0, 0);
    LOADH(Q, v0, ro0, 1);

    // A-frag read: lane (lr,lg); ks: 8 f16 at row lr, col ks*32 + lg*8
    f16x8 a[8];
    {
        const _Float16* ap = lds_a + (size_t)lr * AROW + lg * 8;
#pragma unroll
        for (int ks = 0; ks < 8; ++ks) a[ks] = *(const f16x8*)(ap + ks * 32);
    }

    // 6-step pipelined schedule: P always holds h0, Q always h1
    MFMAH(P, 0);
    LOADH(P, v1, ro1, 0);
    MFMAH(Q, 1);
    LOADH(Q, v1, ro1, 1);
    STAGE(0);
    MFMAH(P, 0);
    LOADH(P, v2, ro2, 0);
    MFMAH(Q, 1);
    LOADH(Q, v2, ro2, 1);
    STAGE(1);
    MFMAH(P, 0);
    MFMAH(Q, 1);
    STAGE(2);

    __syncthreads();

    // coalesced writeout: row r = dy*9+dx -> 64B line
    const int q = (threadIdx.x & 3) * 4;
#pragma unroll
    for (int r = threadIdx.x >> 2; r < 81; r += 48) {
        const float4 v = make_float4(ldso[r][q], ldso[r][q + 1],
                                     ldso[r][q + 2], ldso[r][q + 3]);
        *(float4*)(out + ((size_t)(b * 81 + r) * PLANE) + y * 96 + m0 + q) = v;
    }
#undef LOADH
#undef MFMAH
#undef STAGE
}

// ---------- fallback: round-2 f32 kernel (if ws too small) ------------------
__global__ __launch_bounds__(256) void costvol_f32(const float* __restrict__ f1,
                                                   const float* __restrict__ f2,
                                                   float* __restrict__ out)
{
    __shared__ float lds[2 * 64 * LPAD];
    const int bid = blockIdx.x;
    const int swz = (bid & 7) * (1296 / 8) + (bid >> 3);
    const int dyi = swz % NP;
    const int g   = swz / NP;
    const int w    = threadIdx.x >> 6;
    const int lane = threadIdx.x & 63;
    const int chk = g * 64 + lane;
    const int b   = chk / (NH * 24);
    const int rem = chk - b * (NH * 24);
    const int y   = rem / 24;
    const int x0  = (rem - y * 24) * 4;
    const int y2  = y + dyi - 4;

    float acc[NP][4];
#pragma unroll
    for (int i = 0; i < NP; ++i)
#pragma unroll
        for (int j = 0; j < 4; ++j) acc[i][j] = 0.f;

    if (y2 >= 0 && y2 < NH) {
        const float* p1 = f1 + ((size_t)(b * NC + w * 64) * NH + y) * NW + x0;
        const float* p2 = f2 + ((size_t)(b * NC + w * 64) * NH + y2) * NW + x0;
        const bool hasL = (x0 >= 4);
        const bool hasR = (x0 <= NW - 8);
#pragma unroll 4
        for (int c = 0; c < 64; ++c) {
            const float4 av = *(const float4*)p1;
            const float4 Lv = hasL ? *(const float4*)(p2 - 4) : make_float4(0.f, 0.f, 0.f, 0.f);
            const float4 Mv = *(const float4*)(p2);
            const float4 Rv = hasR ? *(const float4*)(p2 + 4) : make_float4(0.f, 0.f, 0.f, 0.f);
            const float wv[12] = {Lv.x, Lv.y, Lv.z, Lv.w, Mv.x, Mv.y, Mv.z, Mv.w,
                                  Rv.x, Rv.y, Rv.z, Rv.w};
            const float aa[4] = {av.x, av.y, av.z, av.w};
#pragma unroll
            for (int dxi = 0; dxi < NP; ++dxi)
#pragma unroll
                for (int j = 0; j < 4; ++j) acc[dxi][j] += aa[j] * wv[dxi + j];
            p1 += PLANE;
            p2 += PLANE;
        }
    }

    float* reg0 = &lds[0 * 64 * LPAD + lane * LPAD];
    float* reg1 = &lds[1 * 64 * LPAD + lane * LPAD];
    if (w >= 2) {
        float* dst = (w == 2) ? reg0 : reg1;
#pragma unroll
        for (int dxi = 0; dxi < NP; ++dxi)
#pragma unroll
            for (int j = 0; j < 4; ++j) dst[dxi * 4 + j] = acc[dxi][j];
    }
    __syncthreads();
    if (w < 2) {
        const float* src = (w == 0) ? reg0 : reg1;
#pragma unroll
        for (int dxi = 0; dxi < NP; ++dxi)
#pragma unroll
            for (int j = 0; j < 4; ++j) acc[dxi][j] += src[dxi * 4 + j];
    }
    __syncthreads();
    if (w == 1) {
#pragma unroll
        for (int dxi = 0; dxi < NP; ++dxi)
#pragma unroll
            for (int j = 0; j < 4; ++j) reg0[dxi * 4 + j] = acc[dxi][j];
    }
    __syncthreads();
    if (w == 0) {
#pragma unroll
        for (int dxi = 0; dxi < NP; ++dxi)
#pragma unroll
            for (int j = 0; j < 4; ++j) acc[dxi][j] += reg0[dxi * 4 + j];
        float* ob = out + ((size_t)(b * 81 + dyi * 9) * NH + y) * NW + x0;
#pragma unroll
        for (int dxi = 0; dxi < NP; ++dxi) {
            *(float4*)ob = make_float4(acc[dxi][0], acc[dxi][1], acc[dxi][2], acc[dxi][3]);
            ob += PLANE;
        }
    }
}

extern "C" void kernel_launch(void* const* d_in, const int* in_sizes, int n_in,
                              void* d_out, int out_size, void* d_ws, size_t ws_size,
                              hipStream_t stream) {
    const float* f1 = (const float*)d_in[0];
    const float* f2 = (const float*)d_in[1];
    float* out = (float*)d_out;
    if (ws_size >= WS_NEED) {
        _Float16* ws = (_Float16*)d_ws;
        pack_f2<<<dim3(PACK_BLK, 1, 1), dim3(256, 1, 1), 0, stream>>>(f2, ws);
        costvol_mfma<<<dim3(MAIN_BLK, 1, 1), dim3(192, 1, 1), 0, stream>>>(f1, ws, out);
    } else {
        costvol_f32<<<dim3(1296, 1, 1), dim3(256, 1, 1), 0, stream>>>(f1, f2, out);
    }
}

// Round 17
// 38.945 us; speedup vs baseline: 1.0429x; 1.0429x over previous
//
#include <hip/hip_runtime.h>

// Cost volume: corr[b, dyi*9+dxi, y, x] = sum_c f1[b,c,y,x] * f2[b,c,y+dyi-4,x+dxi-4]
// (OOB f2 = 0). B=4, C=256, H=W=96, patch 9x9.
//
// Round 17 = round 15 (best: 38.5us) + n-tile/wave split:
//  - 6 waves/block (384 thr): wave = (dy-triplet d3, n-tile tl). Each wave
//    does 3 dy x 8 B-loads + 8 MFMAs (HALF of R15's 48-load serial chain) and
//    stages only its tile's cells (tile0: lr-mrow in [4,12]; tile1: in
//    [-12,-4] -- disjoint, every cell written exactly once, no reduction).
//  - B-frag buffer per wave halves (32 VGPR) -> ~60 total, 8 waves/SIMD
//    step; thread-cap 5 blocks/CU = 30 waves/CU (was 24).
//  - ldso separate from lds_a (R16's good half): no mid-kernel barrier.
//  - R16's P/Q static pipeline REVERTED (regressed: compiler schedules
//    better; matches guide m131-m141).
//  Pack (f2-only channel-major f16), A LDS-staging, writeout, swizzles
//  unchanged.

typedef _Float16 f16x8 __attribute__((ext_vector_type(8)));
typedef float f32x4 __attribute__((ext_vector_type(4)));

#define NB 4
#define NC 256
#define NH 96
#define NW 96
#define NP 9
#define PLANE (NH * NW)                       // 9216
#define TENS (NB * NH * NW * NC)              // 9,437,184 f16 (f2 only)
#define WS_NEED ((unsigned long long)TENS * 2ull)  // 18,874,368 B
#define TPT4 (TENS / 32)                      // 294,912 pack threads
#define PACK_BLK (TPT4 / 256)                 // 1152
#define MAIN_BLK 2304                         // 4b * 96y * 6mt
#define CGSTR (NW * 8)                        // 768 f16 per cg-plane
#define ROWSTR (32 * CGSTR)                   // 24576 f16 per (b,y) row
#define AROW 272                              // A-tile row stride in f16 (544 B)
#define LPAD 37                               // fallback kernel pad

// ---------- prepass: f2 f32 [b][c][y][x] -> f16 [b][y][cg][x][8] ------------
__global__ __launch_bounds__(256) void pack_f2(const float* __restrict__ f2,
                                               _Float16* __restrict__ ws)
{
    const int e   = blockIdx.x * 256 + threadIdx.x;   // 0 .. 294,911
    const int row = e / 768;                          // b*96 + y   (384)
    const int q   = e % 768;
    const int cg  = q / 24;                           // 0..31
    const int x4  = q % 24;                           // lane-fastest (coalesced)
    const int b   = row / NH;
    const int y   = row % NH;

    const float* sp = f2 + ((size_t)(b * NC + cg * 8) * NH + y) * NW + x4 * 4;
    float vv[8][4];
#pragma unroll
    for (int j = 0; j < 8; ++j) {
        const float4 v = *(const float4*)(sp + (size_t)j * PLANE);
        vv[j][0] = v.x; vv[j][1] = v.y; vv[j][2] = v.z; vv[j][3] = v.w;
    }
    _Float16* dp = ws + ((size_t)row * 32 + cg) * CGSTR + (size_t)x4 * 32;
#pragma unroll
    for (int xi = 0; xi < 4; ++xi) {
        f16x8 o;
#pragma unroll
        for (int j = 0; j < 8; ++j) o[j] = (_Float16)vv[j][xi];
        *(f16x8*)(dp + xi * 8) = o;
    }
}

// ---------- main: MFMA banded Gram, LDS-staged A, 6-wave tile split ---------
__global__ __launch_bounds__(384) void costvol_mfma(const float* __restrict__ f1,
                                                    const _Float16* __restrict__ f2p,
                                                    float* __restrict__ out)
{
    __shared__ _Float16 lds_a[16 * AROW];         // 8704 B
    __shared__ float ldso[81][20];                // 6480 B

    const int bid = blockIdx.x;
    const int swz = (bid & 7) * (MAIN_BLK / 8) + (bid >> 3);
    const int mt  = swz % 6;
    const int y   = (swz / 6) % 96;
    const int b   = swz / 576;

    const int w    = threadIdx.x >> 6;            // wave 0..5
    const int lane = threadIdx.x & 63;
    const int lr   = lane & 15;
    const int lg   = lane >> 4;
    const int m0   = mt * 16;
    const int d3   = w >> 1;                      // dy-triplet 0..2
    const int tl   = w & 1;                       // n-tile 0/1

    // --- cooperative A staging: 1024 float4 tasks over 384 threads ---------
#pragma unroll
    for (int i = 0; i < 3; ++i) {
        const int task = threadIdx.x + i * 384;   // 0..1151
        if (task < 1024) {
            const int c  = task >> 2;
            const int xq = task & 3;
            const float4 v = *(const float4*)(
                f1 + ((size_t)(b * NC + c) * NH + y) * NW + m0 + xq * 4);
            _Float16* d0 = lds_a + (size_t)(xq * 4) * AROW + c;
            d0[0 * AROW] = (_Float16)v.x;
            d0[1 * AROW] = (_Float16)v.y;
            d0[2 * AROW] = (_Float16)v.z;
            d0[3 * AROW] = (_Float16)v.w;
        }
    }
    __syncthreads();

    // A-frag read: lane (lr,lg); ks: 8 f16 at row lr, col ks*32 + lg*8
    f16x8 a[8];
    {
        const _Float16* ap = lds_a + (size_t)lr * AROW + lg * 8;
#pragma unroll
        for (int ks = 0; ks < 8; ++ks) a[ks] = *(const f16x8*)(ap + ks * 32);
    }

    // this wave's n-tile column and its validity
    const int n0   = m0 + (tl ? 8 : -8) + lr;     // x' for this tile
    const bool inN = tl ? (n0 < 96) : (n0 >= 0);
    const int dxoف = 0;                            // (unused)
    const f16x8 bz = {};

#pragma unroll 1
    for (int i = 0; i < 3; ++i) {
        const int dy = d3 * 3 + i;
        const int y2 = y + dy - 4;
        f32x4 acc = {0.f, 0.f, 0.f, 0.f};

        if (y2 >= 0 && y2 < 96) {
            const _Float16* pb = f2p + (size_t)(b * 96 + y2) * ROWSTR
                               + (size_t)lg * CGSTR + (ptrdiff_t)n0 * 8;
            f16x8 B[8];
#pragma unroll
            for (int ks = 0; ks < 8; ++ks)
                B[ks] = inN ? *(const f16x8*)(pb + (size_t)ks * 4 * CGSTR) : bz;
#pragma unroll
            for (int ks = 0; ks < 8; ++ks)
                acc = __builtin_amdgcn_mfma_f32_16x16x32_f16(a[ks], B[ks], acc, 0, 0, 0);
        }

        // stage: D row m = m0+lg*4+reg, col n = lr; dx = lr-mrow + (tl?12:-4)
#pragma unroll
        for (int reg = 0; reg < 4; ++reg) {
            const int mrow = lg * 4 + reg;
            const int dx   = lr - mrow + (tl ? 12 : -4);
            if (dx >= 0 && dx <= 8) ldso[dy * 9 + dx][mrow] = acc[reg];
        }
    }

    __syncthreads();

    // coalesced writeout: row r = dy*9+dx -> 64B line; 384 thr cover 81 rows
    const int r = threadIdx.x >> 2;
    const int q = (threadIdx.x & 3) * 4;
    if (r < 81) {
        const float4 v = make_float4(ldso[r][q], ldso[r][q + 1],
                                     ldso[r][q + 2], ldso[r][q + 3]);
        *(float4*)(out + ((size_t)(b * 81 + r) * PLANE) + y * 96 + m0 + q) = v;
    }
}

// ---------- fallback: round-2 f32 kernel (if ws too small) ------------------
__global__ __launch_bounds__(256) void costvol_f32(const float* __restrict__ f1,
                                                   const float* __restrict__ f2,
                                                   float* __restrict__ out)
{
    __shared__ float lds[2 * 64 * LPAD];
    const int bid = blockIdx.x;
    const int swz = (bid & 7) * (1296 / 8) + (bid >> 3);
    const int dyi = swz % NP;
    const int g   = swz / NP;
    const int w    = threadIdx.x >> 6;
    const int lane = threadIdx.x & 63;
    const int chk = g * 64 + lane;
    const int b   = chk / (NH * 24);
    const int rem = chk - b * (NH * 24);
    const int y   = rem / 24;
    const int x0  = (rem - y * 24) * 4;
    const int y2  = y + dyi - 4;

    float acc[NP][4];
#pragma unroll
    for (int i = 0; i < NP; ++i)
#pragma unroll
        for (int j = 0; j < 4; ++j) acc[i][j] = 0.f;

    if (y2 >= 0 && y2 < NH) {
        const float* p1 = f1 + ((size_t)(b * NC + w * 64) * NH + y) * NW + x0;
        const float* p2 = f2 + ((size_t)(b * NC + w * 64) * NH + y2) * NW + x0;
        const bool hasL = (x0 >= 4);
        const bool hasR = (x0 <= NW - 8);
#pragma unroll 4
        for (int c = 0; c < 64; ++c) {
            const float4 av = *(const float4*)p1;
            const float4 Lv = hasL ? *(const float4*)(p2 - 4) : make_float4(0.f, 0.f, 0.f, 0.f);
            const float4 Mv = *(const float4*)(p2);
            const float4 Rv = hasR ? *(const float4*)(p2 + 4) : make_float4(0.f, 0.f, 0.f, 0.f);
            const float wv[12] = {Lv.x, Lv.y, Lv.z, Lv.w, Mv.x, Mv.y, Mv.z, Mv.w,
                                  Rv.x, Rv.y, Rv.z, Rv.w};
            const float aa[4] = {av.x, av.y, av.z, av.w};
#pragma unroll
            for (int dxi = 0; dxi < NP; ++dxi)
#pragma unroll
                for (int j = 0; j < 4; ++j) acc[dxi][j] += aa[j] * wv[dxi + j];
            p1 += PLANE;
            p2 += PLANE;
        }
    }

    float* reg0 = &lds[0 * 64 * LPAD + lane * LPAD];
    float* reg1 = &lds[1 * 64 * LPAD + lane * LPAD];
    if (w >= 2) {
        float* dst = (w == 2) ? reg0 : reg1;
#pragma unroll
        for (int dxi = 0; dxi < NP; ++dxi)
#pragma unroll
            for (int j = 0; j < 4; ++j) dst[dxi * 4 + j] = acc[dxi][j];
    }
    __syncthreads();
    if (w < 2) {
        const float* src = (w == 0) ? reg0 : reg1;
#pragma unroll
        for (int dxi = 0; dxi < NP; ++dxi)
#pragma unroll
            for (int j = 0; j < 4; ++j) acc[dxi][j] += src[dxi * 4 + j];
    }
    __syncthreads();
    if (w == 1) {
#pragma unroll
        for (int dxi = 0; dxi < NP; ++dxi)
#pragma unroll
            for (int j = 0; j < 4; ++j) reg0[dxi * 4 + j] = acc[dxi][j];
    }
    __syncthreads();
    if (w == 0) {
#pragma unroll
        for (int dxi = 0; dxi < NP; ++dxi)
#pragma unroll
            for (int j = 0; j < 4; ++j) acc[dxi][j] += reg0[dxi * 4 + j];
        float* ob = out + ((size_t)(b * 81 + dyi * 9) * NH + y) * NW + x0;
#pragma unroll
        for (int dxi = 0; dxi < NP; ++dxi) {
            *(float4*)ob = make_float4(acc[dxi][0], acc[dxi][1], acc[dxi][2], acc[dxi][3]);
            ob += PLANE;
        }
    }
}

extern "C" void kernel_launch(void* const* d_in, const int* in_sizes, int n_in,
                              void* d_out, int out_size, void* d_ws, size_t ws_size,
                              hipStream_t stream) {
    const float* f1 = (const float*)d_in[0];
    const float* f2 = (const float*)d_in[1];
    float* out = (float*)d_out;
    if (ws_size >= WS_NEED) {
        _Float16* ws = (_Float16*)d_ws;
        pack_f2<<<dim3(PACK_BLK, 1, 1), dim3(256, 1, 1), 0, stream>>>(f2, ws);
        costvol_mfma<<<dim3(MAIN_BLK, 1, 1), dim3(384, 1, 1), 0, stream>>>(f1, ws, out);
    } else {
        costvol_f32<<<dim3(1296, 1, 1), dim3(256, 1, 1), 0, stream>>>(f1, f2, out);
    }
}